// Round 3
// baseline (868.541 us; speedup 1.0000x reference)
//
#include <hip/hip_runtime.h>
#include <hip/hip_bf16.h>
#include <math.h>

#define T 2048
#define C 128
#define BATCH 8
#define NLAYER 10

typedef short bf16x8 __attribute__((ext_vector_type(8)));
typedef float f32x4 __attribute__((ext_vector_type(4)));
typedef unsigned short u16x4 __attribute__((ext_vector_type(4)));

__device__ __forceinline__ float sigmoidf_(float x) {
    return 1.f / (1.f + __expf(-x));
}
__device__ __forceinline__ float tanhf_(float x) {
    float a = fabsf(x);
    float e = __expf(-2.f * a);
    float t = (1.f - e) / (1.f + e);
    return copysignf(t, x);
}
__device__ __forceinline__ ushort f2bf(float v) {
    __hip_bfloat16 h = __float2bfloat16(v);
    return *reinterpret_cast<ushort*>(&h);
}
__device__ __forceinline__ float bf2f(ushort u) {
    unsigned int x = ((unsigned int)u) << 16;
    return __uint_as_float(x);
}
// async global->LDS, 16B per lane; lds ptr must be wave-uniform (HW adds lane*16)
__device__ __forceinline__ void gl_lds16(const ushort* g, ushort* l) {
    __builtin_amdgcn_global_load_lds(
        (const __attribute__((address_space(1))) unsigned int*)g,
        (__attribute__((address_space(3))) unsigned int*)l, 16, 0, 0);
}

// ---------------- init: h = x*Wc + bc (f32 + bf16) ; skip = 0 ----------------
__global__ void k_init(const float* __restrict__ x, const float* __restrict__ Wc,
                       const float* __restrict__ bc, float* __restrict__ h32,
                       ushort* __restrict__ hb, float* __restrict__ skip) {
    int i = blockIdx.x * 256 + threadIdx.x;   // over B*T*C
    int c = i & 127;
    int pos = i >> 7;
    float v = x[pos] * Wc[c] + bc[c];
    h32[i] = v;
    hb[i] = f2bf(v);
    skip[i] = 0.f;
}

// ---------------- weight preps: coalesced LDS-tiled transposes ----------------
// WGb[l][n 0..255][k = j*128+ci]:  n<128 -> Wt col n ; n>=128 -> Ws col n-128
// grid (4, 4, 60): z = (l*3+j)*2 + s ; block (32, 8)
__global__ void k_prep_wgT(const float* __restrict__ Wt, const float* __restrict__ Ws,
                           ushort* __restrict__ WGb) {
    const int tx = threadIdx.x, ty = threadIdx.y;
    const int z = blockIdx.z, s = z & 1, lj = z >> 1;
    const int l = lj / 3, j = lj % 3;
    const float* src = (s ? Ws : Wt) + (size_t)lj * 128 * 128;
    const int col0 = blockIdx.x * 32, ci0 = blockIdx.y * 32;
    __shared__ float tile[32][33];
    #pragma unroll
    for (int i = 0; i < 4; ++i)
        tile[ty + i * 8][tx] = src[(size_t)(ci0 + ty + i * 8) * 128 + col0 + tx];
    __syncthreads();
    #pragma unroll
    for (int i = 0; i < 4; ++i)
        WGb[((size_t)l * 256 + s * 128 + col0 + ty + i * 8) * 384 + j * 128 + ci0 + tx] =
            f2bf(tile[tx][ty + i * 8]);
}
// WRb[l][n 0..255][ci]: n<128 -> Wskip ; n>=128 -> Wres. grid (4,4,20): z = l*2+s
__global__ void k_prep_wrT(const float* __restrict__ Wskip, const float* __restrict__ Wres,
                           ushort* __restrict__ WRb) {
    const int tx = threadIdx.x, ty = threadIdx.y;
    const int z = blockIdx.z, s = z & 1, l = z >> 1;
    const float* src = (s ? Wres : Wskip) + (size_t)l * 128 * 128;
    const int col0 = blockIdx.x * 32, ci0 = blockIdx.y * 32;
    __shared__ float tile[32][33];
    #pragma unroll
    for (int i = 0; i < 4; ++i)
        tile[ty + i * 8][tx] = src[(size_t)(ci0 + ty + i * 8) * 128 + col0 + tx];
    __syncthreads();
    #pragma unroll
    for (int i = 0; i < 4; ++i)
        WRb[((size_t)l * 256 + s * 128 + col0 + ty + i * 8) * 128 + ci0 + tx] =
            f2bf(tile[tx][ty + i * 8]);
}
// W [R][N] f32 -> Wb [N][R] bf16 (R = 3*KIN). grid (N/32, R/32); block (32,8)
template<int R>
__global__ void k_prep_wT(const float* __restrict__ W, ushort* __restrict__ Wb, int N) {
    const int tx = threadIdx.x, ty = threadIdx.y;
    const int x = blockIdx.x * 32 + tx;      // n
    const int y0 = blockIdx.y * 32;          // k
    __shared__ float tile[32][33];
    #pragma unroll
    for (int i = 0; i < 4; ++i)
        tile[ty + i * 8][tx] = W[(size_t)(y0 + ty + i * 8) * N + x];
    __syncthreads();
    const int n0 = blockIdx.x * 32;
    #pragma unroll
    for (int i = 0; i < 4; ++i)
        Wb[(size_t)(n0 + ty + i * 8) * R + y0 + tx] = f2bf(tile[tx][ty + i * 8]);
}

// skip32 f32 -> padded bf16 [8][2050][128] at row t+1
__global__ void k_skip_pad(const float* __restrict__ in, ushort* __restrict__ skipp) {
    int i = blockIdx.x * 256 + threadIdx.x;   // B*T*C
    int b = i >> 18, rem = i & 262143;
    skipp[(size_t)b * 262400 + 128 + rem] = f2bf(in[i]);
}
// zero pad rows (t=0, t=2049) of out1p [8][2050][2048] and skipp [8][2050][128]
__global__ void k_zero_pads(ushort* __restrict__ out1p, ushort* __restrict__ skipp) {
    int i = blockIdx.x * 256 + threadIdx.x;   // 17408 uint tasks
    if (i < 16384) {
        int ri = i >> 10, col = i & 1023;
        int b = ri >> 1, pr = (ri & 1) ? 2049 : 0;
        ((unsigned int*)out1p)[((size_t)b * 2050 + pr) * 1024 + col] = 0u;
    } else {
        int j = i - 16384;
        int ri = j >> 6, col = j & 63;
        int b = ri >> 1, pr = (ri & 1) ? 2049 : 0;
        ((unsigned int*)skipp)[((size_t)b * 2050 + pr) * 64 + col] = 0u;
    }
}

// ---------------- conditioning precompute, branch-split float4 streaming ----------------
// grid (T/8, 5, 2): z = branch (0 tanh / 1 sigmoid); thread = (k4, tq); 8 batches in regs
__global__ __launch_bounds__(256) void k_cond(
    const float* __restrict__ cond,
    const float* __restrict__ Dt, const float* __restrict__ Bt,
    const float* __restrict__ Ds, const float* __restrict__ Bs,
    const float* __restrict__ bt, const float* __restrict__ bs,
    ushort* __restrict__ z0, int l0)
{
    const int br = blockIdx.z;
    const float* D  = br ? Ds : Dt;
    const float* B_ = br ? Bs : Bt;
    const float* b_ = br ? bs : bt;
    const int l  = l0 + blockIdx.y;
    const int ll = blockIdx.y;
    const int k4 = (threadIdx.x & 31) * 4;   // channel group 0..124
    const int tq = threadIdx.x >> 5;         // 0..7
    const int t  = blockIdx.x * 8 + tq;

    __shared__ float sc[128];
    if (threadIdx.x < 128) sc[threadIdx.x] = cond[threadIdx.x];
    __syncthreads();

    const f32x4 bv = *(const f32x4*)(b_ + l * 128 + k4);
    const f32x4 Bv = *(const f32x4*)(B_ + ((size_t)l * T + t) * 128 + k4);

    f32x4 z[8];
    #pragma unroll
    for (int b = 0; b < 8; ++b) z[b] = bv + Bv;

    const float* dp = D + (((size_t)l * 16) * T + t) * 128 + k4;
    #pragma unroll
    for (int c = 0; c < 16; ++c) {
        const f32x4 dv = *(const f32x4*)(dp + (size_t)c * T * 128);
        #pragma unroll
        for (int b = 0; b < 8; ++b)
            z[b] += sc[b * 16 + c] * dv;
    }

    #pragma unroll
    for (int b = 0; b < 8; ++b) {
        size_t zb = (((size_t)ll * 8 + b) * T + t) * 256;
        u16x4 p;
        #pragma unroll
        for (int j = 0; j < 4; ++j) p[j] = f2bf(z[b][j]);
        *(u16x4*)(z0 + zb + br * 128 + k4) = p;
    }
}

// ---------------- fused MFMA WaveNet layer ----------------
__global__ __launch_bounds__(256) void k_gate(
    const float* __restrict__ h32_in, float* __restrict__ h32_out,
    const ushort* __restrict__ hb_in, ushort* __restrict__ hb_out,
    float* __restrict__ skip32,
    const ushort* __restrict__ WG,   // [256][384] (layer slice)
    const ushort* __restrict__ WR,   // [256][128]
    const ushort* __restrict__ z0l,  // [8][T][256]
    const float* __restrict__ bskip, const float* __restrict__ bres, // [128] slices
    int d)
{
    __shared__ ushort lds[3 * 32 * 136];   // 13056 ushorts = 26112 B
    const int tid  = threadIdx.x;
    const int lane = tid & 63, ln16 = lane & 15, quad = lane >> 4;
    const int wave = tid >> 6;
    const int n_off = wave * 64;
    const int t0 = blockIdx.x * 4;

    // stage A: 3 segs x 32 rows x 256 B
    #pragma unroll
    for (int it = 0; it < 6; ++it) {
        int task = tid + it * 256;        // [0, 1536)
        int part = task & 15;
        int r = (task >> 4) & 31;
        int j = task >> 9;
        int t = t0 + (r >> 3) + (j - 1) * d;
        int b = r & 7;
        uint4 v = make_uint4(0u, 0u, 0u, 0u);
        if (t >= 0 && t < T) v = *(const uint4*)(hb_in + ((size_t)b * T + t) * 128 + part * 8);
        *(uint4*)(&lds[(j * 32 + r) * 136 + part * 8]) = v;
    }
    __syncthreads();

    f32x4 acc[2][4];
    #pragma unroll
    for (int mt = 0; mt < 2; ++mt)
        #pragma unroll
        for (int nt = 0; nt < 4; ++nt)
            acc[mt][nt] = (f32x4){0.f, 0.f, 0.f, 0.f};

    #pragma unroll
    for (int j = 0; j < 3; ++j) {
        #pragma unroll
        for (int kc = 0; kc < 4; ++kc) {
            bf16x8 af[2], bfr[4];
            #pragma unroll
            for (int mt = 0; mt < 2; ++mt)
                af[mt] = *(const bf16x8*)(&lds[(j * 32 + mt * 16 + ln16) * 136 + kc * 32 + quad * 8]);
            #pragma unroll
            for (int nt = 0; nt < 4; ++nt)
                bfr[nt] = *(const bf16x8*)(WG + (size_t)(n_off + nt * 16 + ln16) * 384 + j * 128 + kc * 32 + quad * 8);
            #pragma unroll
            for (int mt = 0; mt < 2; ++mt)
                #pragma unroll
                for (int nt = 0; nt < 4; ++nt)
                    acc[mt][nt] = __builtin_amdgcn_mfma_f32_16x16x32_bf16(af[mt], bfr[nt], acc[mt][nt], 0, 0, 0);
        }
    }
    __syncthreads();   // A segs dead

    // epilogue-1: add z0, stash pre-activations in zbuf (bf16)
    #pragma unroll
    for (int mt = 0; mt < 2; ++mt) {
        #pragma unroll
        for (int nt = 0; nt < 4; ++nt) {
            int n = n_off + nt * 16 + ln16;
            #pragma unroll
            for (int r4 = 0; r4 < 4; ++r4) {
                int row = mt * 16 + quad * 4 + r4;
                int b = row & 7, p = row >> 3;
                float z = acc[mt][nt][r4] + bf2f(z0l[((size_t)b * T + t0 + p) * 256 + n]);
                lds[row * 264 + n] = f2bf(z);
            }
        }
    }
    __syncthreads();

    // gate: g = tanh(zt) * sigmoid(zs) -> gbuf [32][136]
    {
        int r = tid >> 3;              // 0..31
        int k0 = (tid & 7) * 16;       // 0..127 step 16
        #pragma unroll
        for (int kk = 0; kk < 16; ++kk) {
            int k = k0 + kk;
            float zt = bf2f(lds[r * 264 + k]);
            float zs = bf2f(lds[r * 264 + 128 + k]);
            lds[8704 + r * 136 + k] = f2bf(tanhf_(zt) * sigmoidf_(zs));
        }
    }
    __syncthreads();

    // GEMM2: skip/res 1x1 convs, K=128
    f32x4 acc2[2][4];
    #pragma unroll
    for (int mt = 0; mt < 2; ++mt)
        #pragma unroll
        for (int nt = 0; nt < 4; ++nt)
            acc2[mt][nt] = (f32x4){0.f, 0.f, 0.f, 0.f};

    #pragma unroll
    for (int kc = 0; kc < 4; ++kc) {
        bf16x8 af[2], bfr[4];
        #pragma unroll
        for (int mt = 0; mt < 2; ++mt)
            af[mt] = *(const bf16x8*)(&lds[8704 + (mt * 16 + ln16) * 136 + kc * 32 + quad * 8]);
        #pragma unroll
        for (int nt = 0; nt < 4; ++nt)
            bfr[nt] = *(const bf16x8*)(WR + (size_t)(n_off + nt * 16 + ln16) * 128 + kc * 32 + quad * 8);
        #pragma unroll
        for (int mt = 0; mt < 2; ++mt)
            #pragma unroll
            for (int nt = 0; nt < 4; ++nt)
                acc2[mt][nt] = __builtin_amdgcn_mfma_f32_16x16x32_bf16(af[mt], bfr[nt], acc2[mt][nt], 0, 0, 0);
    }

    // epilogue-2: waves 0/1 (n<128) -> skip accum; waves 2/3 -> residual h
    #pragma unroll
    for (int mt = 0; mt < 2; ++mt) {
        #pragma unroll
        for (int nt = 0; nt < 4; ++nt) {
            int n = n_off + nt * 16 + ln16;
            int k = n & 127;
            #pragma unroll
            for (int r4 = 0; r4 < 4; ++r4) {
                int row = mt * 16 + quad * 4 + r4;
                int b = row & 7, p = row >> 3;
                size_t idx = ((size_t)b * T + t0 + p) * 128 + k;
                float v = acc2[mt][nt][r4];
                if (n < 128) {
                    skip32[idx] += v + bskip[k];
                } else {
                    float hv = v + bres[k] + h32_in[idx];
                    h32_out[idx] = hv;
                    hb_out[idx] = f2bf(hv);
                }
            }
        }
    }
}

// ---------------- shared constants for the 3-tap GEMM templates ----------------
#define CV2_AUS 8704      // A tile: 136 rows * 64 us
#define CV2_BUF 33280     // per-buffer ushorts (A 8704 + B 384*64)

// ---------------- conv1 as 3-tap overlapped GEMM, double-buffered gload_lds ----------------
// A = skipp [8][2050][128] bf16 (pad rows zeroed); W = W1b [2048][384]
// out1p[b][t+1][n] = relu(sum_tap A-row(t+tap) . W + b1), K = 384 in 2 chunks of 64
__global__ __launch_bounds__(256) void k_conv1t(
    const ushort* __restrict__ A,
    const ushort* __restrict__ Wb,
    const float* __restrict__ bias,
    ushort* __restrict__ out1p)
{
    __shared__ ushort sh[2 * CV2_BUF];
    const int tid  = threadIdx.x;
    const int lane = tid & 63, ln16 = lane & 15, quad = lane >> 4;
    const int wave = tid >> 6;
    const int wm = wave >> 1, wn = wave & 1;
    const int m0 = blockIdx.x * 128;
    const int b  = blockIdx.y;
    const int n0 = blockIdx.z * 128;
    const size_t aRow0 = (size_t)b * 2050 + m0;   // r=0 <-> t=m0-1

    f32x4 acc[4][4];
    #pragma unroll
    for (int i = 0; i < 4; ++i)
        #pragma unroll
        for (int j = 0; j < 4; ++j) acc[i][j] = (f32x4){0.f, 0.f, 0.f, 0.f};

    auto stage = [&](int d, int c) {
        const int sb = d * CV2_BUF;
        const int k0 = c * 64;
        #pragma unroll
        for (int ps = 0; ps < 4; ++ps) {
            int task = ps * 256 + tid;
            int r = task >> 3, p = task & 7, q = p ^ (r & 7);
            gl_lds16(A + (aRow0 + r) * 128 + k0 + q * 8,
                     &sh[sb + ((ps * 256 + wave * 64) << 3)]);
        }
        if (tid < 64) {
            int task = 1024 + tid;
            int r = task >> 3, p = task & 7, q = p ^ (r & 7);
            gl_lds16(A + (aRow0 + r) * 128 + k0 + q * 8,
                     &sh[sb + (1024 << 3)]);
        }
        #pragma unroll
        for (int ps = 0; ps < 12; ++ps) {
            int task = ps * 256 + tid;
            int rb = task >> 3, p = task & 7, q = p ^ (rb & 7);
            int nl = rb & 127, tap = rb >> 7;
            gl_lds16(Wb + (size_t)(n0 + nl) * 384 + tap * 128 + k0 + q * 8,
                     &sh[sb + CV2_AUS + ((ps * 256 + wave * 64) << 3)]);
        }
    };

    stage(0, 0);
    __syncthreads();

    for (int c = 0; c < 2; ++c) {
        if (c == 0) stage(1, 1);
        const int sb = (c & 1) * CV2_BUF;
        #pragma unroll
        for (int j = 0; j < 3; ++j) {
            #pragma unroll
            for (int kk = 0; kk < 2; ++kk) {
                bf16x8 af[4], bfr[4];
                #pragma unroll
                for (int mt = 0; mt < 4; ++mt) {
                    int r = wm * 64 + mt * 16 + ln16 + j;
                    int s = (kk << 2) | quad;
                    af[mt] = *(const bf16x8*)(&sh[sb + r * 64 + ((s ^ (r & 7)) << 3)]);
                }
                #pragma unroll
                for (int nt = 0; nt < 4; ++nt) {
                    int rb = j * 128 + wn * 64 + nt * 16 + ln16;
                    int s = (kk << 2) | quad;
                    bfr[nt] = *(const bf16x8*)(&sh[sb + CV2_AUS + rb * 64 + ((s ^ (rb & 7)) << 3)]);
                }
                #pragma unroll
                for (int mt = 0; mt < 4; ++mt)
                    #pragma unroll
                    for (int nt = 0; nt < 4; ++nt)
                        acc[mt][nt] = __builtin_amdgcn_mfma_f32_16x16x32_bf16(af[mt], bfr[nt], acc[mt][nt], 0, 0, 0);
            }
        }
        __syncthreads();
    }

    #pragma unroll
    for (int nt = 0; nt < 4; ++nt) {
        int n = n0 + wn * 64 + nt * 16 + ln16;
        float bv = bias[n];
        #pragma unroll
        for (int mt = 0; mt < 4; ++mt) {
            #pragma unroll
            for (int r4 = 0; r4 < 4; ++r4) {
                int m = wm * 64 + mt * 16 + quad * 4 + r4;
                int t = m0 + m;
                float v = fmaxf(acc[mt][nt][r4] + bv, 0.f);
                out1p[((size_t)b * 2050 + 1 + t) * 2048 + n] = f2bf(v);
            }
        }
    }
}

// ---------------- conv2 as 3-tap overlapped GEMM, double-buffered gload_lds ----------------
__global__ __launch_bounds__(256) void k_conv2t(
    const ushort* __restrict__ A,     // out1p
    const ushort* __restrict__ Wb,    // W2b [256][6144]
    const float* __restrict__ bias,   // b2
    float* __restrict__ out2)         // [8][2048][256]
{
    __shared__ ushort sh[2 * CV2_BUF];   // 133120 B
    const int tid  = threadIdx.x;
    const int lane = tid & 63, ln16 = lane & 15, quad = lane >> 4;
    const int wave = tid >> 6;
    const int wm = wave >> 1, wn = wave & 1;
    const int m0 = blockIdx.x * 128;
    const int b  = blockIdx.y;
    const int n0 = blockIdx.z * 128;
    const size_t aRow0 = (size_t)b * 2050 + m0;   // padded row base (t=m0-1 at r=0)

    f32x4 acc[4][4];
    #pragma unroll
    for (int i = 0; i < 4; ++i)
        #pragma unroll
        for (int j = 0; j < 4; ++j) acc[i][j] = (f32x4){0.f, 0.f, 0.f, 0.f};

    auto stage = [&](int d, int cc) {
        const int sb = d * CV2_BUF;
        const int k0 = cc * 64;
        #pragma unroll
        for (int ps = 0; ps < 4; ++ps) {
            int task = ps * 256 + tid;
            int r = task >> 3, p = task & 7, q = p ^ (r & 7);
            gl_lds16(A + (aRow0 + r) * 2048 + k0 + q * 8,
                     &sh[sb + ((ps * 256 + wave * 64) << 3)]);
        }
        if (tid < 64) {
            int task = 1024 + tid;
            int r = task >> 3, p = task & 7, q = p ^ (r & 7);
            gl_lds16(A + (aRow0 + r) * 2048 + k0 + q * 8,
                     &sh[sb + (1024 << 3)]);
        }
        #pragma unroll
        for (int ps = 0; ps < 12; ++ps) {
            int task = ps * 256 + tid;
            int rb = task >> 3, p = task & 7, q = p ^ (rb & 7);
            int nl = rb & 127, tap = rb >> 7;
            gl_lds16(Wb + (size_t)(n0 + nl) * 6144 + tap * 2048 + k0 + q * 8,
                     &sh[sb + CV2_AUS + ((ps * 256 + wave * 64) << 3)]);
        }
    };

    stage(0, 0);
    __syncthreads();

    for (int cc = 0; cc < 32; ++cc) {
        if (cc < 31) stage((cc + 1) & 1, cc + 1);
        const int sb = (cc & 1) * CV2_BUF;
        #pragma unroll
        for (int j = 0; j < 3; ++j) {
            #pragma unroll
            for (int kk = 0; kk < 2; ++kk) {
                bf16x8 af[4], bfr[4];
                #pragma unroll
                for (int mt = 0; mt < 4; ++mt) {
                    int r = wm * 64 + mt * 16 + ln16 + j;
                    int s = (kk << 2) | quad;
                    af[mt] = *(const bf16x8*)(&sh[sb + r * 64 + ((s ^ (r & 7)) << 3)]);
                }
                #pragma unroll
                for (int nt = 0; nt < 4; ++nt) {
                    int rb = j * 128 + wn * 64 + nt * 16 + ln16;
                    int s = (kk << 2) | quad;
                    bfr[nt] = *(const bf16x8*)(&sh[sb + CV2_AUS + rb * 64 + ((s ^ (rb & 7)) << 3)]);
                }
                #pragma unroll
                for (int mt = 0; mt < 4; ++mt)
                    #pragma unroll
                    for (int nt = 0; nt < 4; ++nt)
                        acc[mt][nt] = __builtin_amdgcn_mfma_f32_16x16x32_bf16(af[mt], bfr[nt], acc[mt][nt], 0, 0, 0);
            }
        }
        __syncthreads();
    }

    // epilogue: bias + relu, plain f32 stores
    #pragma unroll
    for (int nt = 0; nt < 4; ++nt) {
        int n = n0 + wn * 64 + nt * 16 + ln16;
        float bv = bias[n];
        #pragma unroll
        for (int mt = 0; mt < 4; ++mt) {
            #pragma unroll
            for (int r4 = 0; r4 < 4; ++r4) {
                int m = wm * 64 + mt * 16 + quad * 4 + r4;
                int t = m0 + m;
                float v = fmaxf(acc[mt][nt][r4] + bv, 0.f);
                out2[((size_t)b * T + t) * 256 + n] = v;
            }
        }
    }
}

// ---------------- head conv3: 256 -> 1, k=1, tanh ----------------
__global__ __launch_bounds__(256) void k_conv3(
    const float* __restrict__ out2, const float* __restrict__ W3,
    const float* __restrict__ b3, float* __restrict__ out)
{
    int wid = threadIdx.x >> 6, lane = threadIdx.x & 63;
    int pos = blockIdx.x * 4 + wid;
    float4 v = *(const float4*)(out2 + (size_t)pos * 256 + lane * 4);
    float4 w = *(const float4*)(W3 + lane * 4);
    float sum = v.x * w.x + v.y * w.y + v.z * w.z + v.w * w.w;
    #pragma unroll
    for (int off = 32; off > 0; off >>= 1) sum += __shfl_down(sum, off);
    if (lane == 0) out[pos] = tanhf_(sum + b3[0]);
}

extern "C" void kernel_launch(void* const* d_in, const int* in_sizes, int n_in,
                              void* d_out, int out_size, void* d_ws, size_t ws_size,
                              hipStream_t stream)
{
    const float* x     = (const float*)d_in[0];
    const float* cond  = (const float*)d_in[1];
    const float* Wc    = (const float*)d_in[2];
    const float* bc    = (const float*)d_in[3];
    const float* Wt    = (const float*)d_in[4];
    const float* bt    = (const float*)d_in[5];
    const float* Ws    = (const float*)d_in[6];
    const float* bs    = (const float*)d_in[7];
    const float* Dt    = (const float*)d_in[8];
    const float* Bt    = (const float*)d_in[9];
    const float* Ds    = (const float*)d_in[10];
    const float* Bs    = (const float*)d_in[11];
    const float* Wskip = (const float*)d_in[12];
    const float* bskip = (const float*)d_in[13];
    const float* Wres  = (const float*)d_in[14];
    const float* bres  = (const float*)d_in[15];
    const float* W1    = (const float*)d_in[16];
    const float* b1    = (const float*)d_in[17];
    const float* W2    = (const float*)d_in[18];
    const float* b2    = (const float*)d_in[19];
    const float* W3    = (const float*)d_in[20];
    const float* b3    = (const float*)d_in[21];
    float* out = (float*)d_out;

    float* ws = (float*)d_ws;
    float*  skip32 = ws;                       // 2M f32
    float*  h32a   = ws + 2097152;             // 2M f32
    float*  h32b   = ws + 4194304;             // 2M f32
    float*  out2   = ws + 6291456;             // 4M f32 (byte 25.2M .. 41.9M)
    ushort* u      = (ushort*)(ws + 10485760); // byte 41.94 MB
    ushort* hba    = u;                        // 2M us (dead after layers)
    ushort* hbb    = u + 2097152;              // 2M us (dead after layers)
    ushort* WGb    = u + 4194304;              // 983,040 us
    ushort* WRb    = u + 5177344;              // 327,680 us
    ushort* W1b    = u + 5505024;              // 786,432 us
    ushort* W2b    = u + 6291456;              // 1,572,864 us (ends u+7,864,320)
    ushort* skipp  = u;                        // [8][2050][128] = 2,099,200 us (hba+edge of hbb, both dead)
    ushort* z0     = u + 9961472;              // 5*8*T*256 = 20,971,520 us (dead at head)
    ushort* out1p  = u + 7864320;              // [8][2050][2048] = 33,587,200 us, overlaps z0 (dead)

    k_init<<<8192, 256, 0, stream>>>(x, Wc, bc, h32a, hba, skip32);
    k_prep_wgT<<<dim3(4, 4, 60), dim3(32, 8), 0, stream>>>(Wt, Ws, WGb);
    k_prep_wrT<<<dim3(4, 4, 20), dim3(32, 8), 0, stream>>>(Wskip, Wres, WRb);
    k_prep_wT<384><<<dim3(64, 12), dim3(32, 8), 0, stream>>>(W1, W1b, 2048);
    k_prep_wT<6144><<<dim3(8, 192), dim3(32, 8), 0, stream>>>(W2, W2b, 256);

    static const int DIL[NLAYER] = {1, 2, 4, 8, 16, 32, 64, 128, 256, 512};
    float*  h32in = h32a;  float*  h32out = h32b;
    ushort* hbin  = hba;   ushort* hbout  = hbb;

    for (int chunk = 0; chunk < 2; ++chunk) {
        int l0 = chunk * 5;
        k_cond<<<dim3(T / 8, 5, 2), 256, 0, stream>>>(cond, Dt, Bt, Ds, Bs, bt, bs, z0, l0);
        for (int l = l0; l < l0 + 5; ++l) {
            k_gate<<<512, 256, 0, stream>>>(
                h32in, h32out, hbin, hbout, skip32,
                WGb + (size_t)l * 256 * 384,
                WRb + (size_t)l * 256 * 128,
                z0 + (size_t)(l - l0) * 8 * T * 256,
                bskip + l * 128, bres + l * 128,
                DIL[l]);
            float* tf = h32in; h32in = h32out; h32out = tf;
            ushort* tu = hbin; hbin = hbout; hbout = tu;
        }
    }

    // head: skip -> padded bf16, pads zeroed, conv1 GEMM, conv2 GEMM, conv3
    k_skip_pad<<<8192, 256, 0, stream>>>(skip32, skipp);
    k_zero_pads<<<68, 256, 0, stream>>>(out1p, skipp);
    k_conv1t<<<dim3(16, 8, 16), 256, 0, stream>>>(skipp, W1b, b1, out1p);
    k_conv2t<<<dim3(16, 8, 2), 256, 0, stream>>>(out1p, W2b, b2, out2);
    k_conv3<<<(BATCH * T) / 4, 256, 0, stream>>>(out2, W3, b3, out);
}

// Round 5
// 812.161 us; speedup vs baseline: 1.0694x; 1.0694x over previous
//
#include <hip/hip_runtime.h>
#include <hip/hip_bf16.h>
#include <math.h>

#define T 2048
#define C 128
#define BATCH 8
#define NLAYER 10

typedef short bf16x8 __attribute__((ext_vector_type(8)));
typedef float f32x4 __attribute__((ext_vector_type(4)));
typedef unsigned short u16x4 __attribute__((ext_vector_type(4)));

struct GPtrs { const ushort* p[NLAYER]; };

__device__ __forceinline__ float sigmoidf_(float x) {
    return 1.f / (1.f + __expf(-x));
}
__device__ __forceinline__ float tanhf_(float x) {
    float a = fabsf(x);
    float e = __expf(-2.f * a);
    float t = (1.f - e) / (1.f + e);
    return copysignf(t, x);
}
__device__ __forceinline__ ushort f2bf(float v) {
    __hip_bfloat16 h = __float2bfloat16(v);
    return *reinterpret_cast<ushort*>(&h);
}
__device__ __forceinline__ float bf2f(ushort u) {
    unsigned int x = ((unsigned int)u) << 16;
    return __uint_as_float(x);
}
// async global->LDS, 16B per lane; lds ptr must be wave-uniform (HW adds lane*16)
__device__ __forceinline__ void gl_lds16(const ushort* g, ushort* l) {
    __builtin_amdgcn_global_load_lds(
        (const __attribute__((address_space(1))) unsigned int*)g,
        (__attribute__((address_space(3))) unsigned int*)l, 16, 0, 0);
}

// ---------------- init: h = x*Wc + bc (f32 + bf16) ----------------
__global__ void k_init(const float* __restrict__ x, const float* __restrict__ Wc,
                       const float* __restrict__ bc, float* __restrict__ h32,
                       ushort* __restrict__ hb) {
    int i = blockIdx.x * 256 + threadIdx.x;   // over B*T*C
    int c = i & 127;
    int pos = i >> 7;
    float v = x[pos] * Wc[c] + bc[c];
    h32[i] = v;
    hb[i] = f2bf(v);
}

// ---------------- weight preps: coalesced LDS-tiled transposes ----------------
// interleaved gate layout: n' = (col>>4)*32 + s*16 + (col&15)
// WGb[l][n' 0..255][k = j*128+ci]; grid (4, 4, 60): z = (l*3+j)*2 + s ; block (32, 8)
__global__ void k_prep_wgT(const float* __restrict__ Wt, const float* __restrict__ Ws,
                           ushort* __restrict__ WGb) {
    const int tx = threadIdx.x, ty = threadIdx.y;
    const int z = blockIdx.z, s = z & 1, lj = z >> 1;
    const int l = lj / 3, j = lj % 3;
    const float* src = (s ? Ws : Wt) + (size_t)lj * 128 * 128;
    const int col0 = blockIdx.x * 32, ci0 = blockIdx.y * 32;
    __shared__ float tile[32][33];
    #pragma unroll
    for (int i = 0; i < 4; ++i)
        tile[ty + i * 8][tx] = src[(size_t)(ci0 + ty + i * 8) * 128 + col0 + tx];
    __syncthreads();
    #pragma unroll
    for (int i = 0; i < 4; ++i) {
        int col = col0 + ty + i * 8;
        int np = ((col >> 4) * 32) + s * 16 + (col & 15);
        WGb[((size_t)l * 256 + np) * 384 + j * 128 + ci0 + tx] = f2bf(tile[tx][ty + i * 8]);
    }
}
// skip/res preps: WSKb[n][l*128+ci] (stacked skip, K=1280) ; WRESb[l][n][ci]
// grid (4,4,20): z = l*2+s (s=0 skip, s=1 res)
__global__ void k_prep_wr2(const float* __restrict__ Wskip, const float* __restrict__ Wres,
                           ushort* __restrict__ WSKb, ushort* __restrict__ WRESb) {
    const int tx = threadIdx.x, ty = threadIdx.y;
    const int z = blockIdx.z, s = z & 1, l = z >> 1;
    const float* src = (s ? Wres : Wskip) + (size_t)l * 128 * 128;
    const int col0 = blockIdx.x * 32, ci0 = blockIdx.y * 32;
    __shared__ float tile[32][33];
    #pragma unroll
    for (int i = 0; i < 4; ++i)
        tile[ty + i * 8][tx] = src[(size_t)(ci0 + ty + i * 8) * 128 + col0 + tx];
    __syncthreads();
    #pragma unroll
    for (int i = 0; i < 4; ++i) {
        int n = col0 + ty + i * 8, ci = ci0 + tx;
        ushort v = f2bf(tile[tx][ty + i * 8]);
        if (s) WRESb[((size_t)l * 128 + n) * 128 + ci] = v;
        else   WSKb[(size_t)n * 1280 + l * 128 + ci] = v;
    }
}
// W [R][N] f32 -> Wb [N][R] bf16 (R = 3*KIN). grid (N/32, R/32); block (32,8)
template<int R>
__global__ void k_prep_wT(const float* __restrict__ W, ushort* __restrict__ Wb, int N) {
    const int tx = threadIdx.x, ty = threadIdx.y;
    const int x = blockIdx.x * 32 + tx;      // n
    const int y0 = blockIdx.y * 32;          // k
    __shared__ float tile[32][33];
    #pragma unroll
    for (int i = 0; i < 4; ++i)
        tile[ty + i * 8][tx] = W[(size_t)(y0 + ty + i * 8) * N + x];
    __syncthreads();
    const int n0 = blockIdx.x * 32;
    #pragma unroll
    for (int i = 0; i < 4; ++i)
        Wb[(size_t)(n0 + ty + i * 8) * R + y0 + tx] = f2bf(tile[tx][ty + i * 8]);
}

// zero pad rows (t=0, t=2049) of out1p [8][2050][2048] and skipp [8][2050][128]
// NOTE: out1p pad rows alias gw[4..9] -> must launch AFTER k_skipsum consumed g.
__global__ void k_zero_pads(ushort* __restrict__ out1p, ushort* __restrict__ skipp) {
    int i = blockIdx.x * 256 + threadIdx.x;   // 17408 uint tasks
    if (i < 16384) {
        int ri = i >> 10, col = i & 1023;
        int b = ri >> 1, pr = (ri & 1) ? 2049 : 0;
        ((unsigned int*)out1p)[((size_t)b * 2050 + pr) * 1024 + col] = 0u;
    } else {
        int j = i - 16384;
        int ri = j >> 6, col = j & 63;
        int b = ri >> 1, pr = (ri & 1) ? 2049 : 0;
        ((unsigned int*)skipp)[((size_t)b * 2050 + pr) * 64 + col] = 0u;
    }
}

// ---------------- conditioning precompute, branch-split float4 streaming ----------------
// z0 written in interleaved layout: n' = (k>>4)*32 + br*16 + (k&15)
__global__ __launch_bounds__(256) void k_cond(
    const float* __restrict__ cond,
    const float* __restrict__ Dt, const float* __restrict__ Bt,
    const float* __restrict__ Ds, const float* __restrict__ Bs,
    const float* __restrict__ bt, const float* __restrict__ bs,
    ushort* __restrict__ z0, int l0)
{
    const int br = blockIdx.z;
    const float* D  = br ? Ds : Dt;
    const float* B_ = br ? Bs : Bt;
    const float* b_ = br ? bs : bt;
    const int l  = l0 + blockIdx.y;
    const int ll = blockIdx.y;
    const int k4 = (threadIdx.x & 31) * 4;   // channel group 0..124
    const int tq = threadIdx.x >> 5;         // 0..7
    const int t  = blockIdx.x * 8 + tq;

    __shared__ float sc[128];
    if (threadIdx.x < 128) sc[threadIdx.x] = cond[threadIdx.x];
    __syncthreads();

    const f32x4 bv = *(const f32x4*)(b_ + l * 128 + k4);
    const f32x4 Bv = *(const f32x4*)(B_ + ((size_t)l * T + t) * 128 + k4);

    f32x4 z[8];
    #pragma unroll
    for (int b = 0; b < 8; ++b) z[b] = bv + Bv;

    const float* dp = D + (((size_t)l * 16) * T + t) * 128 + k4;
    #pragma unroll
    for (int c = 0; c < 16; ++c) {
        const f32x4 dv = *(const f32x4*)(dp + (size_t)c * T * 128);
        #pragma unroll
        for (int b = 0; b < 8; ++b)
            z[b] += sc[b * 16 + c] * dv;
    }

    const int np = ((k4 >> 4) * 32) + br * 16 + (k4 & 15);
    #pragma unroll
    for (int b = 0; b < 8; ++b) {
        size_t zb = (((size_t)ll * 8 + b) * T + t) * 256;
        u16x4 p;
        #pragma unroll
        for (int j = 0; j < 4; ++j) p[j] = f2bf(z[b][j]);
        *(u16x4*)(z0 + zb + np) = p;
    }
}

// ---------------- fused MFMA WaveNet layer (in-register gate, deferred skip) ----------------
// grid 512 (t-tile 4, 8 batches -> M=32 rows), block 256 (4 waves).
// GEMM1: N=256 interleaved [t16|s16|...], K=384. Gate in-reg. g -> global + LDS.
// GEMM2: residual only, N=128, K=128.
__global__ __launch_bounds__(256) void k_gate(
    const float* __restrict__ h32_in, float* __restrict__ h32_out,
    const ushort* __restrict__ hb_in, ushort* __restrict__ hb_out,
    const ushort* __restrict__ WG,   // [256][384] (layer slice, n' interleaved)
    const ushort* __restrict__ WRES, // [128][128]
    const ushort* __restrict__ z0l,  // [8][T][256] (n' interleaved)
    ushort* __restrict__ gout,       // [8][T][128] bf16 gate output
    const float* __restrict__ bres,  // [128] slice
    int d)
{
    __shared__ ushort lds[3 * 32 * 136];   // 13056 ushorts = 26112 B
    const int tid  = threadIdx.x;
    const int lane = tid & 63, ln16 = lane & 15, quad = lane >> 4;
    const int wave = tid >> 6;
    const int n_off = wave * 64;
    const int t0 = blockIdx.x * 4;

    // stage A: 3 segs x 32 rows x 256 B
    #pragma unroll
    for (int it = 0; it < 6; ++it) {
        int task = tid + it * 256;        // [0, 1536)
        int part = task & 15;
        int r = (task >> 4) & 31;
        int j = task >> 9;
        int t = t0 + (r >> 3) + (j - 1) * d;
        int b = r & 7;
        uint4 v = make_uint4(0u, 0u, 0u, 0u);
        if (t >= 0 && t < T) v = *(const uint4*)(hb_in + ((size_t)b * T + t) * 128 + part * 8);
        *(uint4*)(&lds[(j * 32 + r) * 136 + part * 8]) = v;
    }

    // prefetch z0 fragments (32 u16) and residual h (16 f32) - latency hides under GEMM1
    ushort zre[2][4][4];
    float hpre[2][2][4];
    #pragma unroll
    for (int mt = 0; mt < 2; ++mt) {
        #pragma unroll
        for (int r4 = 0; r4 < 4; ++r4) {
            int row = mt * 16 + quad * 4 + r4;
            int b = row & 7, p = row >> 3;
            const ushort* zp = z0l + ((size_t)b * T + t0 + p) * 256 + n_off + ln16;
            #pragma unroll
            for (int nt = 0; nt < 4; ++nt) zre[mt][nt][r4] = zp[nt * 16];
            const float* hp = h32_in + ((size_t)b * T + t0 + p) * 128 + wave * 32 + ln16;
            #pragma unroll
            for (int n2 = 0; n2 < 2; ++n2) hpre[mt][n2][r4] = hp[n2 * 16];
        }
    }
    __syncthreads();

    f32x4 acc[2][4];
    #pragma unroll
    for (int mt = 0; mt < 2; ++mt)
        #pragma unroll
        for (int nt = 0; nt < 4; ++nt)
            acc[mt][nt] = (f32x4){0.f, 0.f, 0.f, 0.f};

    #pragma unroll
    for (int j = 0; j < 3; ++j) {
        #pragma unroll
        for (int kc = 0; kc < 4; ++kc) {
            bf16x8 af[2], bfr[4];
            #pragma unroll
            for (int mt = 0; mt < 2; ++mt)
                af[mt] = *(const bf16x8*)(&lds[(j * 32 + mt * 16 + ln16) * 136 + kc * 32 + quad * 8]);
            #pragma unroll
            for (int nt = 0; nt < 4; ++nt)
                bfr[nt] = *(const bf16x8*)(WG + (size_t)(n_off + nt * 16 + ln16) * 384 + j * 128 + kc * 32 + quad * 8);
            #pragma unroll
            for (int mt = 0; mt < 2; ++mt)
                #pragma unroll
                for (int nt = 0; nt < 4; ++nt)
                    acc[mt][nt] = __builtin_amdgcn_mfma_f32_16x16x32_bf16(af[mt], bfr[nt], acc[mt][nt], 0, 0, 0);
        }
    }

    // in-register gate: pair (nt=2i, nt=2i+1) share channel k = wave*32 + i*16 + ln16
    ushort gfr[2][2][4];
    #pragma unroll
    for (int mt = 0; mt < 2; ++mt)
        #pragma unroll
        for (int i = 0; i < 2; ++i)
            #pragma unroll
            for (int r4 = 0; r4 < 4; ++r4) {
                float zt = acc[mt][2 * i][r4]     + bf2f(zre[mt][2 * i][r4]);
                float zs = acc[mt][2 * i + 1][r4] + bf2f(zre[mt][2 * i + 1][r4]);
                gfr[mt][i][r4] = f2bf(tanhf_(zt) * sigmoidf_(zs));
            }
    // g -> global (fire-and-forget; consumed by k_skipsum later)
    #pragma unroll
    for (int mt = 0; mt < 2; ++mt)
        #pragma unroll
        for (int i = 0; i < 2; ++i)
            #pragma unroll
            for (int r4 = 0; r4 < 4; ++r4) {
                int row = mt * 16 + quad * 4 + r4;
                int b = row & 7, p = row >> 3;
                gout[((size_t)b * T + t0 + p) * 128 + wave * 32 + i * 16 + ln16] = gfr[mt][i][r4];
            }
    __syncthreads();   // A segs dead

    // g -> LDS gbuf [32][136] (seg-2 area) for GEMM2 A-fragments
    #pragma unroll
    for (int mt = 0; mt < 2; ++mt)
        #pragma unroll
        for (int i = 0; i < 2; ++i)
            #pragma unroll
            for (int r4 = 0; r4 < 4; ++r4) {
                int row = mt * 16 + quad * 4 + r4;
                lds[8704 + row * 136 + wave * 32 + i * 16 + ln16] = gfr[mt][i][r4];
            }
    __syncthreads();

    // GEMM2: residual 1x1 conv, N=128 (wave covers 32), K=128
    f32x4 acc2[2][2];
    #pragma unroll
    for (int mt = 0; mt < 2; ++mt)
        #pragma unroll
        for (int n2 = 0; n2 < 2; ++n2)
            acc2[mt][n2] = (f32x4){0.f, 0.f, 0.f, 0.f};

    #pragma unroll
    for (int kc = 0; kc < 4; ++kc) {
        bf16x8 af[2], bfr[2];
        #pragma unroll
        for (int mt = 0; mt < 2; ++mt)
            af[mt] = *(const bf16x8*)(&lds[8704 + (mt * 16 + ln16) * 136 + kc * 32 + quad * 8]);
        #pragma unroll
        for (int n2 = 0; n2 < 2; ++n2)
            bfr[n2] = *(const bf16x8*)(WRES + (size_t)(wave * 32 + n2 * 16 + ln16) * 128 + kc * 32 + quad * 8);
        #pragma unroll
        for (int mt = 0; mt < 2; ++mt)
            #pragma unroll
            for (int n2 = 0; n2 < 2; ++n2)
                acc2[mt][n2] = __builtin_amdgcn_mfma_f32_16x16x32_bf16(af[mt], bfr[n2], acc2[mt][n2], 0, 0, 0);
    }

    // epilogue: residual h update
    #pragma unroll
    for (int n2 = 0; n2 < 2; ++n2) {
        int n = wave * 32 + n2 * 16 + ln16;
        float bv = bres[n];
        #pragma unroll
        for (int mt = 0; mt < 2; ++mt) {
            #pragma unroll
            for (int r4 = 0; r4 < 4; ++r4) {
                int row = mt * 16 + quad * 4 + r4;
                int b = row & 7, p = row >> 3;
                size_t idx = ((size_t)b * T + t0 + p) * 128 + n;
                float hv = acc2[mt][n2][r4] + bv + hpre[mt][n2][r4];
                h32_out[idx] = hv;
                hb_out[idx] = f2bf(hv);
            }
        }
    }
}

// ---------------- skip-sum GEMM: skipp = bf16( G(16384x1280) . WSK + sum bskip ) ----------------
// grid (32, 8): t-tile 64, batch. block 256 = 4 waves (wm rows32, wn n64). K = 1280, 20 chunks.
__global__ __launch_bounds__(256) void k_skipsum(
    GPtrs gp, const ushort* __restrict__ Wsk,   // [128][1280]
    const float* __restrict__ bskip,            // [10][128]
    ushort* __restrict__ skipp)                 // [8][2050][128], rows t+1
{
    __shared__ ushort sh[2 * 12288];   // 49152 B: A 64x64 + B 128x64 per buffer
    const int tid  = threadIdx.x;
    const int lane = tid & 63, ln16 = lane & 15, quad = lane >> 4;
    const int wave = tid >> 6;
    const int wm = wave >> 1, wn = wave & 1;
    const int m0 = blockIdx.x * 64;
    const int b  = blockIdx.y;

    f32x4 acc[2][4];
    #pragma unroll
    for (int i = 0; i < 2; ++i)
        #pragma unroll
        for (int j = 0; j < 4; ++j) acc[i][j] = (f32x4){0.f, 0.f, 0.f, 0.f};

    auto stage = [&](int dd, int kc) {
        const int sb = dd * 12288;
        const int l = kc >> 1, k0 = (kc & 1) * 64;
        const ushort* gl = gp.p[l] + ((size_t)b * T + m0) * 128 + k0;
        #pragma unroll
        for (int ps = 0; ps < 2; ++ps) {
            int task = ps * 256 + tid;
            int r = task >> 3, p = task & 7, q = p ^ (r & 7);
            gl_lds16(gl + (size_t)r * 128 + q * 8, &sh[sb + ((ps * 256 + wave * 64) << 3)]);
        }
        #pragma unroll
        for (int ps = 0; ps < 4; ++ps) {
            int task = ps * 256 + tid;
            int r = task >> 3, p = task & 7, q = p ^ (r & 7);
            gl_lds16(Wsk + (size_t)r * 1280 + l * 128 + k0 + q * 8,
                     &sh[sb + 4096 + ((ps * 256 + wave * 64) << 3)]);
        }
    };

    stage(0, 0);
    __syncthreads();

    for (int kc = 0; kc < 20; ++kc) {
        if (kc < 19) stage((kc + 1) & 1, kc + 1);
        const int sb = (kc & 1) * 12288;
        #pragma unroll
        for (int kk = 0; kk < 2; ++kk) {
            bf16x8 af[2], bfr[4];
            int s = (kk << 2) | quad;
            #pragma unroll
            for (int mt = 0; mt < 2; ++mt) {
                int r = wm * 32 + mt * 16 + ln16;
                af[mt] = *(const bf16x8*)(&sh[sb + r * 64 + ((s ^ (r & 7)) << 3)]);
            }
            #pragma unroll
            for (int nt = 0; nt < 4; ++nt) {
                int rb = wn * 64 + nt * 16 + ln16;
                bfr[nt] = *(const bf16x8*)(&sh[sb + 4096 + rb * 64 + ((s ^ (rb & 7)) << 3)]);
            }
            #pragma unroll
            for (int mt = 0; mt < 2; ++mt)
                #pragma unroll
                for (int nt = 0; nt < 4; ++nt)
                    acc[mt][nt] = __builtin_amdgcn_mfma_f32_16x16x32_bf16(af[mt], bfr[nt], acc[mt][nt], 0, 0, 0);
        }
        __syncthreads();
    }

    #pragma unroll
    for (int nt = 0; nt < 4; ++nt) {
        int n = wn * 64 + nt * 16 + ln16;
        float bv = 0.f;
        #pragma unroll
        for (int l = 0; l < NLAYER; ++l) bv += bskip[l * 128 + n];
        #pragma unroll
        for (int mt = 0; mt < 2; ++mt) {
            #pragma unroll
            for (int r4 = 0; r4 < 4; ++r4) {
                int t = m0 + wm * 32 + mt * 16 + quad * 4 + r4;
                skipp[((size_t)b * 2050 + 1 + t) * 128 + n] = f2bf(acc[mt][nt][r4] + bv);
            }
        }
    }
}

// ---------------- shared constants for the 3-tap GEMM templates ----------------
#define CV2_AUS 8704      // A tile: 136 rows * 64 us
#define CV2_BUF 33280     // per-buffer ushorts (A 8704 + B 384*64)

// ---------------- conv1 as 3-tap overlapped GEMM, double-buffered gload_lds ----------------
__global__ __launch_bounds__(256) void k_conv1t(
    const ushort* __restrict__ A,     // skipp [8][2050][128]
    const ushort* __restrict__ Wb,    // W1b [2048][384]
    const float* __restrict__ bias,
    ushort* __restrict__ out1p)
{
    __shared__ ushort sh[2 * CV2_BUF];
    const int tid  = threadIdx.x;
    const int lane = tid & 63, ln16 = lane & 15, quad = lane >> 4;
    const int wave = tid >> 6;
    const int wm = wave >> 1, wn = wave & 1;
    const int m0 = blockIdx.x * 128;
    const int b  = blockIdx.y;
    const int n0 = blockIdx.z * 128;
    const size_t aRow0 = (size_t)b * 2050 + m0;   // r=0 <-> t=m0-1

    f32x4 acc[4][4];
    #pragma unroll
    for (int i = 0; i < 4; ++i)
        #pragma unroll
        for (int j = 0; j < 4; ++j) acc[i][j] = (f32x4){0.f, 0.f, 0.f, 0.f};

    auto stage = [&](int dd, int c) {
        const int sb = dd * CV2_BUF;
        const int k0 = c * 64;
        #pragma unroll
        for (int ps = 0; ps < 4; ++ps) {
            int task = ps * 256 + tid;
            int r = task >> 3, p = task & 7, q = p ^ (r & 7);
            gl_lds16(A + (aRow0 + r) * 128 + k0 + q * 8,
                     &sh[sb + ((ps * 256 + wave * 64) << 3)]);
        }
        if (tid < 64) {
            int task = 1024 + tid;
            int r = task >> 3, p = task & 7, q = p ^ (r & 7);
            gl_lds16(A + (aRow0 + r) * 128 + k0 + q * 8,
                     &sh[sb + (1024 << 3)]);
        }
        #pragma unroll
        for (int ps = 0; ps < 12; ++ps) {
            int task = ps * 256 + tid;
            int rb = task >> 3, p = task & 7, q = p ^ (rb & 7);
            int nl = rb & 127, tap = rb >> 7;
            gl_lds16(Wb + (size_t)(n0 + nl) * 384 + tap * 128 + k0 + q * 8,
                     &sh[sb + CV2_AUS + ((ps * 256 + wave * 64) << 3)]);
        }
    };

    stage(0, 0);
    __syncthreads();

    for (int c = 0; c < 2; ++c) {
        if (c == 0) stage(1, 1);
        const int sb = (c & 1) * CV2_BUF;
        #pragma unroll
        for (int j = 0; j < 3; ++j) {
            #pragma unroll
            for (int kk = 0; kk < 2; ++kk) {
                bf16x8 af[4], bfr[4];
                #pragma unroll
                for (int mt = 0; mt < 4; ++mt) {
                    int r = wm * 64 + mt * 16 + ln16 + j;
                    int s = (kk << 2) | quad;
                    af[mt] = *(const bf16x8*)(&sh[sb + r * 64 + ((s ^ (r & 7)) << 3)]);
                }
                #pragma unroll
                for (int nt = 0; nt < 4; ++nt) {
                    int rb = j * 128 + wn * 64 + nt * 16 + ln16;
                    int s = (kk << 2) | quad;
                    bfr[nt] = *(const bf16x8*)(&sh[sb + CV2_AUS + rb * 64 + ((s ^ (rb & 7)) << 3)]);
                }
                #pragma unroll
                for (int mt = 0; mt < 4; ++mt)
                    #pragma unroll
                    for (int nt = 0; nt < 4; ++nt)
                        acc[mt][nt] = __builtin_amdgcn_mfma_f32_16x16x32_bf16(af[mt], bfr[nt], acc[mt][nt], 0, 0, 0);
            }
        }
        __syncthreads();
    }

    #pragma unroll
    for (int nt = 0; nt < 4; ++nt) {
        int n = n0 + wn * 64 + nt * 16 + ln16;
        float bv = bias[n];
        #pragma unroll
        for (int mt = 0; mt < 4; ++mt) {
            #pragma unroll
            for (int r4 = 0; r4 < 4; ++r4) {
                int m = wm * 64 + mt * 16 + quad * 4 + r4;
                int t = m0 + m;
                float v = fmaxf(acc[mt][nt][r4] + bv, 0.f);
                out1p[((size_t)b * 2050 + 1 + t) * 2048 + n] = f2bf(v);
            }
        }
    }
}

// ---------------- conv2 as 3-tap overlapped GEMM, double-buffered gload_lds ----------------
__global__ __launch_bounds__(256) void k_conv2t(
    const ushort* __restrict__ A,     // out1p
    const ushort* __restrict__ Wb,    // W2b [256][6144]
    const float* __restrict__ bias,   // b2
    float* __restrict__ out2)         // [8][2048][256]
{
    __shared__ ushort sh[2 * CV2_BUF];   // 133120 B
    const int tid  = threadIdx.x;
    const int lane = tid & 63, ln16 = lane & 15, quad = lane >> 4;
    const int wave = tid >> 6;
    const int wm = wave >> 1, wn = wave & 1;
    const int m0 = blockIdx.x * 128;
    const int b  = blockIdx.y;
    const int n0 = blockIdx.z * 128;
    const size_t aRow0 = (size_t)b * 2050 + m0;

    f32x4 acc[4][4];
    #pragma unroll
    for (int i = 0; i < 4; ++i)
        #pragma unroll
        for (int j = 0; j < 4; ++j) acc[i][j] = (f32x4){0.f, 0.f, 0.f, 0.f};

    auto stage = [&](int dd, int cc) {
        const int sb = dd * CV2_BUF;
        const int k0 = cc * 64;
        #pragma unroll
        for (int ps = 0; ps < 4; ++ps) {
            int task = ps * 256 + tid;
            int r = task >> 3, p = task & 7, q = p ^ (r & 7);
            gl_lds16(A + (aRow0 + r) * 2048 + k0 + q * 8,
                     &sh[sb + ((ps * 256 + wave * 64) << 3)]);
        }
        if (tid < 64) {
            int task = 1024 + tid;
            int r = task >> 3, p = task & 7, q = p ^ (r & 7);
            gl_lds16(A + (aRow0 + r) * 2048 + k0 + q * 8,
                     &sh[sb + (1024 << 3)]);
        }
        #pragma unroll
        for (int ps = 0; ps < 12; ++ps) {
            int task = ps * 256 + tid;
            int rb = task >> 3, p = task & 7, q = p ^ (rb & 7);
            int nl = rb & 127, tap = rb >> 7;
            gl_lds16(Wb + (size_t)(n0 + nl) * 6144 + tap * 2048 + k0 + q * 8,
                     &sh[sb + CV2_AUS + ((ps * 256 + wave * 64) << 3)]);
        }
    };

    stage(0, 0);
    __syncthreads();

    for (int cc = 0; cc < 32; ++cc) {
        if (cc < 31) stage((cc + 1) & 1, cc + 1);
        const int sb = (cc & 1) * CV2_BUF;
        #pragma unroll
        for (int j = 0; j < 3; ++j) {
            #pragma unroll
            for (int kk = 0; kk < 2; ++kk) {
                bf16x8 af[4], bfr[4];
                #pragma unroll
                for (int mt = 0; mt < 4; ++mt) {
                    int r = wm * 64 + mt * 16 + ln16 + j;
                    int s = (kk << 2) | quad;
                    af[mt] = *(const bf16x8*)(&sh[sb + r * 64 + ((s ^ (r & 7)) << 3)]);
                }
                #pragma unroll
                for (int nt = 0; nt < 4; ++nt) {
                    int rb = j * 128 + wn * 64 + nt * 16 + ln16;
                    int s = (kk << 2) | quad;
                    bfr[nt] = *(const bf16x8*)(&sh[sb + CV2_AUS + rb * 64 + ((s ^ (rb & 7)) << 3)]);
                }
                #pragma unroll
                for (int mt = 0; mt < 4; ++mt)
                    #pragma unroll
                    for (int nt = 0; nt < 4; ++nt)
                        acc[mt][nt] = __builtin_amdgcn_mfma_f32_16x16x32_bf16(af[mt], bfr[nt], acc[mt][nt], 0, 0, 0);
            }
        }
        __syncthreads();
    }

    #pragma unroll
    for (int nt = 0; nt < 4; ++nt) {
        int n = n0 + wn * 64 + nt * 16 + ln16;
        float bv = bias[n];
        #pragma unroll
        for (int mt = 0; mt < 4; ++mt) {
            #pragma unroll
            for (int r4 = 0; r4 < 4; ++r4) {
                int m = wm * 64 + mt * 16 + quad * 4 + r4;
                int t = m0 + m;
                float v = fmaxf(acc[mt][nt][r4] + bv, 0.f);
                out2[((size_t)b * T + t) * 256 + n] = v;
            }
        }
    }
}

// ---------------- head conv3: 256 -> 1, k=1, tanh ----------------
__global__ __launch_bounds__(256) void k_conv3(
    const float* __restrict__ out2, const float* __restrict__ W3,
    const float* __restrict__ b3, float* __restrict__ out)
{
    int wid = threadIdx.x >> 6, lane = threadIdx.x & 63;
    int pos = blockIdx.x * 4 + wid;
    float4 v = *(const float4*)(out2 + (size_t)pos * 256 + lane * 4);
    float4 w = *(const float4*)(W3 + lane * 4);
    float sum = v.x * w.x + v.y * w.y + v.z * w.z + v.w * w.w;
    #pragma unroll
    for (int off = 32; off > 0; off >>= 1) sum += __shfl_down(sum, off);
    if (lane == 0) out[pos] = tanhf_(sum + b3[0]);
}

extern "C" void kernel_launch(void* const* d_in, const int* in_sizes, int n_in,
                              void* d_out, int out_size, void* d_ws, size_t ws_size,
                              hipStream_t stream)
{
    const float* x     = (const float*)d_in[0];
    const float* cond  = (const float*)d_in[1];
    const float* Wc    = (const float*)d_in[2];
    const float* bc    = (const float*)d_in[3];
    const float* Wt    = (const float*)d_in[4];
    const float* bt    = (const float*)d_in[5];
    const float* Ws    = (const float*)d_in[6];
    const float* bs    = (const float*)d_in[7];
    const float* Dt    = (const float*)d_in[8];
    const float* Bt    = (const float*)d_in[9];
    const float* Ds    = (const float*)d_in[10];
    const float* Bs    = (const float*)d_in[11];
    const float* Wskip = (const float*)d_in[12];
    const float* bskip = (const float*)d_in[13];
    const float* Wres  = (const float*)d_in[14];
    const float* bres  = (const float*)d_in[15];
    const float* W1    = (const float*)d_in[16];
    const float* b1    = (const float*)d_in[17];
    const float* W2    = (const float*)d_in[18];
    const float* b2    = (const float*)d_in[19];
    const float* W3    = (const float*)d_in[20];
    const float* b3    = (const float*)d_in[21];
    float* out = (float*)d_out;

    char* wsb = (char*)d_ws;
    // byte-offset workspace map (peak 116.5 MB < proven 129 MB):
    float*  h32a  = (float*)(wsb + 0);              // 8.39 MB
    float*  h32b  = (float*)(wsb + 8388608);        // 8.39 MB
    float*  out2  = (float*)(wsb + 16777216);       // 16.78 MB (head; overlays gbuf l=0..3)
    ushort* hba   = (ushort*)(wsb + 33554432);      // 4.19 MB
    ushort* hbb   = (ushort*)(wsb + 37748736);      // 4.19 MB
    ushort* WGb   = (ushort*)(wsb + 41943040);      // 1.97 MB
    ushort* WRESb = (ushort*)(wsb + 43909120);      // 0.33 MB
    ushort* W1b   = (ushort*)(wsb + 44236800);      // 1.57 MB
    ushort* W2b   = (ushort*)(wsb + 45809664);      // 3.15 MB
    ushort* WSKb  = (ushort*)(wsb + 48955392);      // 0.33 MB
    ushort* z0    = (ushort*)(wsb + 49283072);      // 41.94 MB (5-layer chunk, reused)
    // g buffers: l=0..3 in out2 area (time-disjoint), l=4..9 after z0
    GPtrs gp;
    ushort* gw[NLAYER];
    for (int l = 0; l < 4; ++l)
        gw[l] = (ushort*)(wsb + 16777216 + (size_t)l * 4194304);
    for (int l = 4; l < NLAYER; ++l)
        gw[l] = (ushort*)(wsb + 91226112 + (size_t)(l - 4) * 4194304);
    for (int l = 0; l < NLAYER; ++l) gp.p[l] = gw[l];
    // head-only overlays
    ushort* skipp = hba;                            // [8][2050][128] (hba + 4 KB of hbb, both dead)
    ushort* out1p = z0;                             // [8][2050][2048] (z0 + gbuf4-9; gbuf dead AFTER k_skipsum)

    k_init<<<8192, 256, 0, stream>>>(x, Wc, bc, h32a, hba);
    k_prep_wgT<<<dim3(4, 4, 60), dim3(32, 8), 0, stream>>>(Wt, Ws, WGb);
    k_prep_wr2<<<dim3(4, 4, 20), dim3(32, 8), 0, stream>>>(Wskip, Wres, WSKb, WRESb);
    k_prep_wT<384><<<dim3(64, 12), dim3(32, 8), 0, stream>>>(W1, W1b, 2048);
    k_prep_wT<6144><<<dim3(8, 192), dim3(32, 8), 0, stream>>>(W2, W2b, 256);

    static const int DIL[NLAYER] = {1, 2, 4, 8, 16, 32, 64, 128, 256, 512};
    float*  h32in = h32a;  float*  h32out = h32b;
    ushort* hbin  = hba;   ushort* hbout  = hbb;

    for (int chunk = 0; chunk < 2; ++chunk) {
        int l0 = chunk * 5;
        k_cond<<<dim3(T / 8, 5, 2), 256, 0, stream>>>(cond, Dt, Bt, Ds, Bs, bt, bs, z0, l0);
        for (int l = l0; l < l0 + 5; ++l) {
            k_gate<<<512, 256, 0, stream>>>(
                h32in, h32out, hbin, hbout,
                WGb + (size_t)l * 256 * 384,
                WRESb + (size_t)l * 128 * 128,
                z0 + (size_t)(l - l0) * 8 * T * 256,
                gw[l],
                bres + l * 128,
                DIL[l]);
            float* tf = h32in; h32in = h32out; h32out = tf;
            ushort* tu = hbin; hbin = hbout; hbout = tu;
        }
    }

    // head: skip-sum GEMM FIRST (consumes g buffers), then pad-zeroing (overlays g),
    // then conv1 GEMM, conv2 GEMM, conv3
    k_skipsum<<<dim3(32, 8), 256, 0, stream>>>(gp, WSKb, bskip, skipp);
    k_zero_pads<<<68, 256, 0, stream>>>(out1p, skipp);
    k_conv1t<<<dim3(16, 8, 16), 256, 0, stream>>>(skipp, W1b, b1, out1p);
    k_conv2t<<<dim3(16, 8, 2), 256, 0, stream>>>(out1p, W2b, b2, out2);
    k_conv3<<<(BATCH * T) / 4, 256, 0, stream>>>(out2, W3, b3, out);
}